// Round 1
// baseline (61.884 us; speedup 1.0000x reference)
//
#include <hip/hip_runtime.h>

#define B_ 8
#define C_ 64
#define H_ 192
#define W_ 320
#define HW_ (H_*W_)
#define OUT_ELEMS ((size_t)B_*C_*H_*W_)

// Per-batch parameter block stored in d_ws as doubles:
// [m00, m01, m02, m10, m12, m20, m22, s, cx] (m11=m21=0 omitted)
__global__ void bev_setup_kernel(const float* __restrict__ h_cam,
                                 const float* __restrict__ p_cam,
                                 const float* __restrict__ fu,
                                 const float* __restrict__ fv,
                                 const int*   __restrict__ plane_h,
                                 double* __restrict__ params,
                                 float*  __restrict__ scales_out,
                                 float*  __restrict__ centers_out) {
    int b = threadIdx.x;
    if (b >= B_) return;
    const double D  = 1e-16;
    const double cu = W_ / 2.0;   // 160
    const double cv = H_ / 2.0;   // 96
    double h   = (double)h_cam[b];
    double p   = (double)p_cam[b];
    double dfu = (double)fu[b];
    double dfv = (double)fv[b];
    double ph  = (double)plane_h[0];
    double h_ref = h - ph;
    double sp = sin(p), cp = cos(p);

    double m00 = cu * cp;
    double m01 = -dfu;
    double m02 = cu * h_ref * sp;
    double m10 = cv * cp - dfv * sp;
    double m12 = h_ref * (dfv * cp + cv * sp);
    double m20 = cp;
    double m22 = h_ref * sp;
    double s   = h / (sp * (cv * cp + dfv * sp) + D);
    double cx  = h * cp / (sp + D);

    double* pp = params + (size_t)b * 10;
    pp[0] = m00; pp[1] = m01; pp[2] = m02;
    pp[3] = m10; pp[4] = m12;
    pp[5] = m20; pp[6] = m22;
    pp[7] = s;   pp[8] = cx;

    scales_out[b] = (float)s;
    centers_out[b*3 + 0] = (float)cx;
    centers_out[b*3 + 1] = 0.0f;
    centers_out[b*3 + 2] = 1.0f;
}

__global__ __launch_bounds__(256)
void bev_main_kernel(const float* __restrict__ x,
                     const double* __restrict__ params,
                     float* __restrict__ out) {
    const int b   = blockIdx.y;
    const int pix = blockIdx.x * 256 + threadIdx.x;   // [0, H*W)
    const int v   = pix / W_;
    const int u   = pix - v * W_;

    const double* pp = params + (size_t)b * 10;
    const double m00 = pp[0], m01 = pp[1], m02 = pp[2];
    const double m10 = pp[3], m12 = pp[4];
    const double m20 = pp[5], m22 = pp[6];
    const double s   = pp[7], cx  = pp[8];

    // world coords for this pixel
    const double wx = cx + s * ((double)(H_/2) - (double)v);
    const double wy =      s * ((double)(W_/2) - (double)u);
    const double t0 = m00 * wx + m01 * wy + m02;
    const double t1 = m10 * wx + m12;
    const double t2 = m20 * wx + m22;
    const double su = t0 / t2;
    const double sv = t1 / t2;

    const double fsu = floor(su), fsv = floor(sv);
    // Non-degenerate bilinear cell iff su in [0, W-1) and sv in [0, H-1).
    // Otherwise at least one axis clips both taps to the same index and the
    // reference's weights cancel exactly -> output is 0.
    const bool inr = (su >= 0.0) && (su < (double)(W_-1)) &&
                     (sv >= 0.0) && (sv < (double)(H_-1));

    float wa, wb, wc, wd;
    int u0i, v0i;
    if (inr) {
        u0i = (int)fsu;
        v0i = (int)fsv;
        const float du0 = (float)(su - fsu);
        const float dv0 = (float)(sv - fsv);
        const float du1 = (float)((double)u0i + 1.0 - su);
        const float dv1 = (float)((double)v0i + 1.0 - sv);
        wa = dv1 * du1;   // (v0, u0)
        wb = dv0 * du1;   // (v1, u0)
        wc = dv1 * du0;   // (v0, u1)
        wd = dv0 * du0;   // (v1, u1)
    } else {
        u0i = 0; v0i = 0;
        wa = wb = wc = wd = 0.0f;
    }

    const int i00 = v0i * W_ + u0i;
    const float* __restrict__ xb = x + (size_t)b * C_ * HW_;
    float* __restrict__ ob = out + (size_t)b * C_ * HW_ + (size_t)pix;

    #pragma unroll 4
    for (int c = 0; c < C_; ++c) {
        const float* __restrict__ xc = xb + (size_t)c * HW_;
        const float ga = xc[i00];
        const float gb = xc[i00 + W_];
        const float gc = xc[i00 + 1];
        const float gd = xc[i00 + W_ + 1];
        ob[(size_t)c * HW_] = wa * ga + wb * gb + wc * gc + wd * gd;
    }
}

extern "C" void kernel_launch(void* const* d_in, const int* in_sizes, int n_in,
                              void* d_out, int out_size, void* d_ws, size_t ws_size,
                              hipStream_t stream) {
    const float* x     = (const float*)d_in[0];
    const float* h_cam = (const float*)d_in[1];
    const float* p_cam = (const float*)d_in[2];
    const float* fu    = (const float*)d_in[3];
    const float* fv    = (const float*)d_in[4];
    const int*   ph    = (const int*)  d_in[5];

    float* out = (float*)d_out;
    float* scales_out  = out + OUT_ELEMS;        // 8 floats
    float* centers_out = out + OUT_ELEMS + B_;   // 24 floats
    double* params = (double*)d_ws;              // 8 * 10 doubles = 640 B

    bev_setup_kernel<<<1, 64, 0, stream>>>(h_cam, p_cam, fu, fv, ph,
                                           params, scales_out, centers_out);

    dim3 grid(HW_ / 256, B_);   // 240 x 8 blocks, 1 thread per pixel
    bev_main_kernel<<<grid, 256, 0, stream>>>(x, params, out);
}

// Round 3
// 46.817 us; speedup vs baseline: 1.3218x; 1.3218x over previous
//
#include <hip/hip_runtime.h>

#define B_ 8
#define C_ 64
#define H_ 192
#define W_ 320
#define HW_ (H_*W_)
#define OUT_ELEMS ((size_t)B_*C_*H_*W_)

#define CSPLIT 8            // channel chunks per batch
#define CPB    (C_/CSPLIT)  // 8 channels per block
#define PIXT   4            // pixels per thread (float4 store)

typedef float f32x4 __attribute__((ext_vector_type(4)));

// Per-batch parameter block stored in d_ws as doubles:
// [m00, m01, m02, m10, m12, m20, m22, s, cx] (m11=m21=0 omitted)
__global__ void bev_setup_kernel(const float* __restrict__ h_cam,
                                 const float* __restrict__ p_cam,
                                 const float* __restrict__ fu,
                                 const float* __restrict__ fv,
                                 const int*   __restrict__ plane_h,
                                 double* __restrict__ params,
                                 float*  __restrict__ scales_out,
                                 float*  __restrict__ centers_out) {
    int b = threadIdx.x;
    if (b >= B_) return;
    const double D  = 1e-16;
    const double cu = W_ / 2.0;   // 160
    const double cv = H_ / 2.0;   // 96
    double h   = (double)h_cam[b];
    double p   = (double)p_cam[b];
    double dfu = (double)fu[b];
    double dfv = (double)fv[b];
    double ph  = (double)plane_h[0];
    double h_ref = h - ph;
    double sp = sin(p), cp = cos(p);

    double m00 = cu * cp;
    double m01 = -dfu;
    double m02 = cu * h_ref * sp;
    double m10 = cv * cp - dfv * sp;
    double m12 = h_ref * (dfv * cp + cv * sp);
    double m20 = cp;
    double m22 = h_ref * sp;
    double s   = h / (sp * (cv * cp + dfv * sp) + D);
    double cx  = h * cp / (sp + D);

    double* pp = params + (size_t)b * 10;
    pp[0] = m00; pp[1] = m01; pp[2] = m02;
    pp[3] = m10; pp[4] = m12;
    pp[5] = m20; pp[6] = m22;
    pp[7] = s;   pp[8] = cx;

    scales_out[b] = (float)s;
    centers_out[b*3 + 0] = (float)cx;
    centers_out[b*3 + 1] = 0.0f;
    centers_out[b*3 + 2] = 1.0f;
}

__global__ __launch_bounds__(256)
void bev_main_kernel(const float* __restrict__ x,
                     const double* __restrict__ params,
                     float* __restrict__ out) {
    const int bc   = blockIdx.y;
    const int b    = bc >> 3;                 // CSPLIT = 8
    const int c0   = (bc & 7) * CPB;
    const int pix0 = (blockIdx.x * 256 + threadIdx.x) * PIXT;
    const int v    = pix0 / W_;               // 4 | W, so all 4 pixels same row
    const int u    = pix0 - v * W_;

    const double* pp = params + (size_t)b * 10;
    const double m00 = pp[0], m01 = pp[1], m02 = pp[2];
    const double m10 = pp[3], m12 = pp[4];
    const double m20 = pp[5], m22 = pp[6];
    const double s   = pp[7], cx  = pp[8];

    // Row-level geometry: t2 and sv depend only on v; su is affine in u.
    const double wx     = cx + s * ((double)(H_/2) - (double)v);
    const double t2     = m20 * wx + m22;
    const double inv_t2 = 1.0 / t2;
    const double sv     = (m10 * wx + m12) * inv_t2;
    const double su_c   = (m00 * wx + m02) * inv_t2;   // constant part
    const double su_k   = m01 * s * inv_t2;            // coeff of (cu - u)

    const bool rowin = (sv >= 0.0) && (sv < (double)(H_-1));
    int v0i = 0;
    float dv0 = 0.f, dv1 = 0.f;
    if (rowin) {
        v0i = (int)sv;                          // sv >= 0
        dv0 = (float)(sv - (double)v0i);
        dv1 = (float)((double)(v0i + 1) - sv);
    }

    float wa[PIXT], wb[PIXT], wc[PIXT], wd[PIXT];
    int   base[PIXT];
    #pragma unroll
    for (int k = 0; k < PIXT; ++k) {
        const double su = su_c + su_k * ((double)(W_/2) - (double)(u + k));
        const bool inr = rowin && (su >= 0.0) && (su < (double)(W_-1));
        int u0i = 0;
        float du0 = 0.f, du1 = 0.f;
        if (inr) {
            u0i = (int)su;
            du0 = (float)(su - (double)u0i);
            du1 = (float)((double)(u0i + 1) - su);
        }
        wa[k] = dv1 * du1;   // (v0, u0)
        wb[k] = dv0 * du1;   // (v1, u0)
        wc[k] = dv1 * du0;   // (v0, u1)
        wd[k] = dv0 * du0;   // (v1, u1)
        base[k] = v0i * W_ + u0i;
    }

    const float* __restrict__ xb = x   + ((size_t)(b * C_ + c0)) * HW_;
    float* __restrict__       ob = out + ((size_t)(b * C_ + c0)) * HW_ + (size_t)pix0;

    #pragma unroll 2
    for (int c = 0; c < CPB; ++c) {
        const float* __restrict__ xc = xb + (size_t)c * HW_;
        f32x4 r;
        r.x = wa[0]*xc[base[0]] + wb[0]*xc[base[0]+W_] + wc[0]*xc[base[0]+1] + wd[0]*xc[base[0]+W_+1];
        r.y = wa[1]*xc[base[1]] + wb[1]*xc[base[1]+W_] + wc[1]*xc[base[1]+1] + wd[1]*xc[base[1]+W_+1];
        r.z = wa[2]*xc[base[2]] + wb[2]*xc[base[2]+W_] + wc[2]*xc[base[2]+1] + wd[2]*xc[base[2]+W_+1];
        r.w = wa[3]*xc[base[3]] + wb[3]*xc[base[3]+W_] + wc[3]*xc[base[3]+1] + wd[3]*xc[base[3]+W_+1];
        __builtin_nontemporal_store(r, (f32x4*)(ob + (size_t)c * HW_));
    }
}

extern "C" void kernel_launch(void* const* d_in, const int* in_sizes, int n_in,
                              void* d_out, int out_size, void* d_ws, size_t ws_size,
                              hipStream_t stream) {
    const float* x     = (const float*)d_in[0];
    const float* h_cam = (const float*)d_in[1];
    const float* p_cam = (const float*)d_in[2];
    const float* fu    = (const float*)d_in[3];
    const float* fv    = (const float*)d_in[4];
    const int*   ph    = (const int*)  d_in[5];

    float* out = (float*)d_out;
    float* scales_out  = out + OUT_ELEMS;        // 8 floats
    float* centers_out = out + OUT_ELEMS + B_;   // 24 floats
    double* params = (double*)d_ws;              // 8 * 10 doubles = 640 B

    bev_setup_kernel<<<1, 64, 0, stream>>>(h_cam, p_cam, fu, fv, ph,
                                           params, scales_out, centers_out);

    dim3 grid(HW_ / (256 * PIXT), B_ * CSPLIT);  // 60 x 64 blocks
    bev_main_kernel<<<grid, 256, 0, stream>>>(x, params, out);
}

// Round 4
// 46.527 us; speedup vs baseline: 1.3301x; 1.0062x over previous
//
#include <hip/hip_runtime.h>

#define B_ 8
#define C_ 64
#define H_ 192
#define W_ 320
#define HW_ (H_*W_)
#define OUT_ELEMS ((size_t)B_*C_*H_*W_)

#define CSPLIT 8            // channel chunks per batch
#define CPB    (C_/CSPLIT)  // 8 channels per block
#define CGRP   4            // channels per load-group (16 loads in flight)
#define PIXT   4            // pixels per thread (float4 store)

typedef float f32x4 __attribute__((ext_vector_type(4)));

// Per-batch parameter block stored in d_ws as doubles:
// [m00, m01, m02, m10, m12, m20, m22, s, cx] (m11=m21=0 omitted)
__global__ void bev_setup_kernel(const float* __restrict__ h_cam,
                                 const float* __restrict__ p_cam,
                                 const float* __restrict__ fu,
                                 const float* __restrict__ fv,
                                 const int*   __restrict__ plane_h,
                                 double* __restrict__ params,
                                 float*  __restrict__ scales_out,
                                 float*  __restrict__ centers_out) {
    int b = threadIdx.x;
    if (b >= B_) return;
    const double D  = 1e-16;
    const double cu = W_ / 2.0;   // 160
    const double cv = H_ / 2.0;   // 96
    double h   = (double)h_cam[b];
    double p   = (double)p_cam[b];
    double dfu = (double)fu[b];
    double dfv = (double)fv[b];
    double ph  = (double)plane_h[0];
    double h_ref = h - ph;
    double sp = sin(p), cp = cos(p);

    double m00 = cu * cp;
    double m01 = -dfu;
    double m02 = cu * h_ref * sp;
    double m10 = cv * cp - dfv * sp;
    double m12 = h_ref * (dfv * cp + cv * sp);
    double m20 = cp;
    double m22 = h_ref * sp;
    double s   = h / (sp * (cv * cp + dfv * sp) + D);
    double cx  = h * cp / (sp + D);

    double* pp = params + (size_t)b * 10;
    pp[0] = m00; pp[1] = m01; pp[2] = m02;
    pp[3] = m10; pp[4] = m12;
    pp[5] = m20; pp[6] = m22;
    pp[7] = s;   pp[8] = cx;

    scales_out[b] = (float)s;
    centers_out[b*3 + 0] = (float)cx;
    centers_out[b*3 + 1] = 0.0f;
    centers_out[b*3 + 2] = 1.0f;
}

__global__ __launch_bounds__(256, 4)
void bev_main_kernel(const float* __restrict__ x,
                     const double* __restrict__ params,
                     float* __restrict__ out) {
    const int bc   = blockIdx.y;
    const int b    = bc >> 3;                 // CSPLIT = 8
    const int c0   = (bc & 7) * CPB;
    const int pix0 = (blockIdx.x * 256 + threadIdx.x) * PIXT;
    const int v    = pix0 / W_;               // 4 | W, so all 4 pixels same row
    const int u    = pix0 - v * W_;

    const double* pp = params + (size_t)b * 10;
    const double m00 = pp[0], m01 = pp[1], m02 = pp[2];
    const double m10 = pp[3], m12 = pp[4];
    const double m20 = pp[5], m22 = pp[6];
    const double s   = pp[7], cx  = pp[8];

    // Row-level geometry: t2 and sv depend only on v; su is affine in u.
    const double wx     = cx + s * ((double)(H_/2) - (double)v);
    const double t2     = m20 * wx + m22;
    const double inv_t2 = 1.0 / t2;
    const double sv     = (m10 * wx + m12) * inv_t2;
    const double su_c   = (m00 * wx + m02) * inv_t2;   // constant part
    const double su_k   = m01 * s * inv_t2;            // coeff of (cu - u)

    const bool rowin = (sv >= 0.0) && (sv < (double)(H_-1));
    int v0i = 0;
    float dv0 = 0.f, dv1 = 0.f;
    if (rowin) {
        v0i = (int)sv;                          // sv >= 0
        dv0 = (float)(sv - (double)v0i);
        dv1 = (float)((double)(v0i + 1) - sv);
    }

    float wa[PIXT], wb[PIXT], wc[PIXT], wd[PIXT];
    int   base[PIXT];
    #pragma unroll
    for (int k = 0; k < PIXT; ++k) {
        const double su = su_c + su_k * ((double)(W_/2) - (double)(u + k));
        const bool inr = rowin && (su >= 0.0) && (su < (double)(W_-1));
        int u0i = 0;
        float du0 = 0.f, du1 = 0.f;
        if (inr) {
            u0i = (int)su;
            du0 = (float)(su - (double)u0i);
            du1 = (float)((double)(u0i + 1) - su);
        }
        wa[k] = dv1 * du1;   // (v0, u0)
        wb[k] = dv0 * du1;   // (v1, u0)
        wc[k] = dv1 * du0;   // (v0, u1)
        wd[k] = dv0 * du0;   // (v1, u1)
        base[k] = v0i * W_ + u0i;
    }

    const float* __restrict__ xb = x   + ((size_t)(b * C_ + c0)) * HW_;
    float* __restrict__       ob = out + ((size_t)(b * C_ + c0)) * HW_ + (size_t)pix0;

    // Two fully-unrolled groups of CGRP channels: issue all 16 gather loads
    // of a group before consuming any (independent -> compiler keeps them in
    // flight), then FMA-combine and nontemporal-store.
    #pragma unroll
    for (int g = 0; g < CPB / CGRP; ++g) {
        float ga[CGRP][PIXT], gb[CGRP][PIXT], gc[CGRP][PIXT], gd[CGRP][PIXT];
        #pragma unroll
        for (int c = 0; c < CGRP; ++c) {
            const float* __restrict__ xc = xb + (size_t)(g * CGRP + c) * HW_;
            #pragma unroll
            for (int k = 0; k < PIXT; ++k) {
                ga[c][k] = xc[base[k]];
                gb[c][k] = xc[base[k] + W_];
                gc[c][k] = xc[base[k] + 1];
                gd[c][k] = xc[base[k] + W_ + 1];
            }
        }
        #pragma unroll
        for (int c = 0; c < CGRP; ++c) {
            f32x4 r;
            r.x = wa[0]*ga[c][0] + wb[0]*gb[c][0] + wc[0]*gc[c][0] + wd[0]*gd[c][0];
            r.y = wa[1]*ga[c][1] + wb[1]*gb[c][1] + wc[1]*gc[c][1] + wd[1]*gd[c][1];
            r.z = wa[2]*ga[c][2] + wb[2]*gb[c][2] + wc[2]*gc[c][2] + wd[2]*gd[c][2];
            r.w = wa[3]*ga[c][3] + wb[3]*gb[c][3] + wc[3]*gc[c][3] + wd[3]*gd[c][3];
            __builtin_nontemporal_store(r, (f32x4*)(ob + (size_t)(g * CGRP + c) * HW_));
        }
    }
}

extern "C" void kernel_launch(void* const* d_in, const int* in_sizes, int n_in,
                              void* d_out, int out_size, void* d_ws, size_t ws_size,
                              hipStream_t stream) {
    const float* x     = (const float*)d_in[0];
    const float* h_cam = (const float*)d_in[1];
    const float* p_cam = (const float*)d_in[2];
    const float* fu    = (const float*)d_in[3];
    const float* fv    = (const float*)d_in[4];
    const int*   ph    = (const int*)  d_in[5];

    float* out = (float*)d_out;
    float* scales_out  = out + OUT_ELEMS;        // 8 floats
    float* centers_out = out + OUT_ELEMS + B_;   // 24 floats
    double* params = (double*)d_ws;              // 8 * 10 doubles = 640 B

    bev_setup_kernel<<<1, 64, 0, stream>>>(h_cam, p_cam, fu, fv, ph,
                                           params, scales_out, centers_out);

    dim3 grid(HW_ / (256 * PIXT), B_ * CSPLIT);  // 60 x 64 blocks
    bev_main_kernel<<<grid, 256, 0, stream>>>(x, params, out);
}

// Round 5
// 46.169 us; speedup vs baseline: 1.3404x; 1.0078x over previous
//
#include <hip/hip_runtime.h>

#define B_ 8
#define C_ 64
#define H_ 192
#define W_ 320
#define HW_ (H_*W_)
#define OUT_ELEMS ((size_t)B_*C_*H_*W_)

#define CSPLIT 8            // channel chunks per batch
#define CPB    (C_/CSPLIT)  // 8 channels per block
#define CGRP   4            // channels per load-group
#define PIXT   4            // pixels per thread (float4 store)

typedef float f32x4 __attribute__((ext_vector_type(4)));

// 8-byte tap-pair with only 4-byte alignment guarantee: compiler emits
// global_load_dwordx2 (unaligned-access-mode is default on amdhsa).
struct __attribute__((packed, aligned(4))) fpair { float lo, hi; };

// Per-batch parameter block stored in d_ws as doubles:
// [m00, m01, m02, m10, m12, m20, m22, s, cx] (m11=m21=0 omitted)
__global__ void bev_setup_kernel(const float* __restrict__ h_cam,
                                 const float* __restrict__ p_cam,
                                 const float* __restrict__ fu,
                                 const float* __restrict__ fv,
                                 const int*   __restrict__ plane_h,
                                 double* __restrict__ params,
                                 float*  __restrict__ scales_out,
                                 float*  __restrict__ centers_out) {
    int b = threadIdx.x;
    if (b >= B_) return;
    const double D  = 1e-16;
    const double cu = W_ / 2.0;   // 160
    const double cv = H_ / 2.0;   // 96
    double h   = (double)h_cam[b];
    double p   = (double)p_cam[b];
    double dfu = (double)fu[b];
    double dfv = (double)fv[b];
    double ph  = (double)plane_h[0];
    double h_ref = h - ph;
    double sp = sin(p), cp = cos(p);

    double m00 = cu * cp;
    double m01 = -dfu;
    double m02 = cu * h_ref * sp;
    double m10 = cv * cp - dfv * sp;
    double m12 = h_ref * (dfv * cp + cv * sp);
    double m20 = cp;
    double m22 = h_ref * sp;
    double s   = h / (sp * (cv * cp + dfv * sp) + D);
    double cx  = h * cp / (sp + D);

    double* pp = params + (size_t)b * 10;
    pp[0] = m00; pp[1] = m01; pp[2] = m02;
    pp[3] = m10; pp[4] = m12;
    pp[5] = m20; pp[6] = m22;
    pp[7] = s;   pp[8] = cx;

    scales_out[b] = (float)s;
    centers_out[b*3 + 0] = (float)cx;
    centers_out[b*3 + 1] = 0.0f;
    centers_out[b*3 + 2] = 1.0f;
}

__global__ __launch_bounds__(256, 4)
void bev_main_kernel(const float* __restrict__ x,
                     const double* __restrict__ params,
                     float* __restrict__ out) {
    const int bc   = blockIdx.y;
    const int b    = bc >> 3;                 // CSPLIT = 8
    const int c0   = (bc & 7) * CPB;
    const int pix0 = (blockIdx.x * 256 + threadIdx.x) * PIXT;
    const int v    = pix0 / W_;               // 4 | W, so all 4 pixels same row
    const int u    = pix0 - v * W_;

    const double* pp = params + (size_t)b * 10;
    const double m00 = pp[0], m01 = pp[1], m02 = pp[2];
    const double m10 = pp[3], m12 = pp[4];
    const double m20 = pp[5], m22 = pp[6];
    const double s   = pp[7], cx  = pp[8];

    // Row-level geometry: t2 and sv depend only on v; su is affine in u.
    const double wx     = cx + s * ((double)(H_/2) - (double)v);
    const double t2     = m20 * wx + m22;
    const double inv_t2 = 1.0 / t2;
    const double sv     = (m10 * wx + m12) * inv_t2;
    const double su_c   = (m00 * wx + m02) * inv_t2;   // constant part
    const double su_k   = m01 * s * inv_t2;            // coeff of (cu - u)

    const bool rowin = (sv >= 0.0) && (sv < (double)(H_-1));
    int v0i = 0;
    float dv0 = 0.f, dv1 = 0.f;
    if (rowin) {
        v0i = (int)sv;                          // sv >= 0
        dv0 = (float)(sv - (double)v0i);
        dv1 = (float)((double)(v0i + 1) - sv);
    }

    float wa[PIXT], wb[PIXT], wc[PIXT], wd[PIXT];
    int   base[PIXT];
    #pragma unroll
    for (int k = 0; k < PIXT; ++k) {
        const double su = su_c + su_k * ((double)(W_/2) - (double)(u + k));
        const bool inr = rowin && (su >= 0.0) && (su < (double)(W_-1));
        int u0i = 0;
        float du0 = 0.f, du1 = 0.f;
        if (inr) {
            u0i = (int)su;
            du0 = (float)(su - (double)u0i);
            du1 = (float)((double)(u0i + 1) - su);
        }
        wa[k] = dv1 * du1;   // (v0, u0)
        wb[k] = dv0 * du1;   // (v1, u0)
        wc[k] = dv1 * du0;   // (v0, u1)
        wd[k] = dv0 * du0;   // (v1, u1)
        base[k] = v0i * W_ + u0i;
    }

    const float* __restrict__ xb = x   + ((size_t)(b * C_ + c0)) * HW_;
    float* __restrict__       ob = out + ((size_t)(b * C_ + c0)) * HW_ + (size_t)pix0;

    // Each pixel's 4 taps = 2 horizontally-adjacent pairs -> 2 dwordx2 gathers.
    #pragma unroll
    for (int g = 0; g < CPB / CGRP; ++g) {
        fpair tp[CGRP][PIXT], bp[CGRP][PIXT];
        #pragma unroll
        for (int c = 0; c < CGRP; ++c) {
            const float* __restrict__ xc = xb + (size_t)(g * CGRP + c) * HW_;
            #pragma unroll
            for (int k = 0; k < PIXT; ++k) {
                tp[c][k] = *(const fpair*)(xc + base[k]);        // (v0,u0),(v0,u1)
                bp[c][k] = *(const fpair*)(xc + base[k] + W_);   // (v1,u0),(v1,u1)
            }
        }
        #pragma unroll
        for (int c = 0; c < CGRP; ++c) {
            f32x4 r;
            r.x = wa[0]*tp[c][0].lo + wc[0]*tp[c][0].hi + wb[0]*bp[c][0].lo + wd[0]*bp[c][0].hi;
            r.y = wa[1]*tp[c][1].lo + wc[1]*tp[c][1].hi + wb[1]*bp[c][1].lo + wd[1]*bp[c][1].hi;
            r.z = wa[2]*tp[c][2].lo + wc[2]*tp[c][2].hi + wb[2]*bp[c][2].lo + wd[2]*bp[c][2].hi;
            r.w = wa[3]*tp[c][3].lo + wc[3]*tp[c][3].hi + wb[3]*bp[c][3].lo + wd[3]*bp[c][3].hi;
            __builtin_nontemporal_store(r, (f32x4*)(ob + (size_t)(g * CGRP + c) * HW_));
        }
    }
}

extern "C" void kernel_launch(void* const* d_in, const int* in_sizes, int n_in,
                              void* d_out, int out_size, void* d_ws, size_t ws_size,
                              hipStream_t stream) {
    const float* x     = (const float*)d_in[0];
    const float* h_cam = (const float*)d_in[1];
    const float* p_cam = (const float*)d_in[2];
    const float* fu    = (const float*)d_in[3];
    const float* fv    = (const float*)d_in[4];
    const int*   ph    = (const int*)  d_in[5];

    float* out = (float*)d_out;
    float* scales_out  = out + OUT_ELEMS;        // 8 floats
    float* centers_out = out + OUT_ELEMS + B_;   // 24 floats
    double* params = (double*)d_ws;              // 8 * 10 doubles = 640 B

    bev_setup_kernel<<<1, 64, 0, stream>>>(h_cam, p_cam, fu, fv, ph,
                                           params, scales_out, centers_out);

    dim3 grid(HW_ / (256 * PIXT), B_ * CSPLIT);  // 60 x 64 blocks
    bev_main_kernel<<<grid, 256, 0, stream>>>(x, params, out);
}